// Round 16
// baseline (2079.754 us; speedup 1.0000x reference)
//
#include <hip/hip_runtime.h>
#include <hip/hip_bf16.h>
#include <stdint.h>

// TextRNN: 2-layer tanh RNN. B=128,T=512,H=512,E=256,V=32000.
// R16 = R15 (spread flags + runtime NS; 1737us) + depth-2 pipelined flag poll:
//   two staggered flag samples in flight -> sampling period ~RTT/2 (+1 sleep per
//   round), detection lag ~0.75 RTT vs ~1.5 RTT. Stray poll loads at exit are
//   retired in-order under the next volley's vmcnt; their regs pinned (PIN2).
//   This retests R13's idea in the FIXED flag layout: R13's 2x regression was
//   depth-4 x PACKED flags (line contention, proven by R14's -11%).
// R15 post-mortem: NS=8 flat -> h1 never paced; h0's own legs (drain+sig+detect+
//   volley+compute) are the pacer; detect is the one leg software can shrink.

#define VOCAB 32000
#define EMB   256
#define HID   512
#define BATCH 128
#define SEQ   512
#define SLOT  8192          // one time-slot: 64 units * 16 rows * 8 shorts
#define FSTRIDE 32          // words between flags: one flag per 128B line

typedef __attribute__((ext_vector_type(8))) short bf16x8;
typedef __attribute__((ext_vector_type(4))) float f32x4;

__device__ inline short f2bf(float f) {
  union { float f; uint32_t u; } v; v.f = f;
  uint32_t u = v.u;
  uint32_t r = (u + 0x7FFFu + ((u >> 16) & 1u)) >> 16;
  return (short)r;
}
__device__ inline float bf2f(unsigned short s) {
  union { uint32_t u; float f; } v; v.u = ((uint32_t)s) << 16;
  return v.f;
}
__device__ inline bf16x8 cvt8(f32x4 x0, f32x4 x1) {
  bf16x8 r;
  r[0]=f2bf(x0[0]); r[1]=f2bf(x0[1]); r[2]=f2bf(x0[2]); r[3]=f2bf(x0[3]);
  r[4]=f2bf(x1[0]); r[5]=f2bf(x1[1]); r[6]=f2bf(x1[2]); r[7]=f2bf(x1[3]);
  return r;
}
__device__ inline f32x4 mfma16(bf16x8 a, bf16x8 b, f32x4 c) {
  return __builtin_amdgcn_mfma_f32_16x16x32_bf16(a, b, c, 0, 0, 0);
}
__device__ inline float fast_tanh(float x) {
  x = fminf(30.f, fmaxf(-30.f, x));
  float e = __expf(2.f * x);
  return (e - 1.f) * __builtin_amdgcn_rcpf(e + 1.f);
}

#define VMCNT0  asm volatile("s_waitcnt vmcnt(0)" ::: "memory")
#define VMCNT16 asm volatile("s_waitcnt vmcnt(16)" ::: "memory")
#define LGKM0   asm volatile("s_waitcnt lgkmcnt(0)" ::: "memory")
#define SCHED0  __builtin_amdgcn_sched_barrier(0)
#define PIN2(a,b) asm volatile("" :: "v"(a), "v"(b))

__device__ inline void st16(unsigned short* p, bf16x8 v) {
  asm volatile("global_store_dwordx4 %0, %1, off sc0 sc1" :: "v"(p), "v"(v) : "memory");
}
__device__ inline void sig(unsigned* p, unsigned v) {
  asm volatile("global_store_dword %0, %1, off sc0 sc1" :: "v"(p), "v"(v) : "memory");
}
// Depth-2 pipelined poll. Lanes 0-15: f0[lane*FS] >= t0 ; lanes 16-31:
// f1[(lane-16)*FS] >= t1 ; lanes 32-63 idle. On return up to ONE stray flag
// load is in flight writing v0 or v1 -- caller must retire it under a later
// vmcnt and keep v0/v1 pinned (PIN2) until then.
__device__ __forceinline__ void pollD2(const unsigned* f0, const unsigned* f1,
                                       unsigned t0, unsigned t1,
                                       unsigned& v0, unsigned& v1) {
  const int lane = threadIdx.x & 63;
  const bool poller = (lane < 32);
  bool ok = !poller;
  const unsigned* fp = (lane < 16) ? (f0 + lane * FSTRIDE)
                                   : (f1 + ((lane - 16) & 15) * FSTRIDE);
  const unsigned tgt = (lane < 16) ? t0 : t1;
#define FISS(r) asm volatile("global_load_dword %0, %1, off sc0 sc1" \
                             : "=v"(r) : "v"(fp) : "memory")
  if (poller) { FISS(v0); FISS(v1); }
  int guard = 0;
  while (true) {
    asm volatile("s_waitcnt vmcnt(1)" ::: "memory"); SCHED0;   // v0 ready
    if (!ok) ok = (v0 >= tgt);
    if (__ballot(ok) == ~0ull) break;
    if (poller) FISS(v0);
    asm volatile("s_waitcnt vmcnt(1)" ::: "memory"); SCHED0;   // v1 ready
    if (!ok) ok = (v1 >= tgt);
    if (__ballot(ok) == ~0ull) break;
    if (poller) FISS(v1);
    __builtin_amdgcn_s_sleep(1);
    if (++guard > 30000) break;   // fail visibly, never hang the harness
  }
#undef FISS
}

__global__ void k_init(unsigned* __restrict__ p, int n) {
  int i = blockIdx.x * 256 + threadIdx.x;
  if (i < n) p[i] = 0u;
}

// ---- CW = C @ W_ax.T  (M=32000, N=512, K=256), bf16 out ----
__global__ void __launch_bounds__(256) k_cw(const float* __restrict__ C,
                                            const float* __restrict__ Wax,
                                            unsigned short* __restrict__ CW) {
  const int tid = threadIdx.x, lane = tid & 63, wv = tid >> 6;
  const int l15 = lane & 15, l4 = lane >> 4;
  const int row = blockIdx.x * 64 + wv * 16 + l15;
  bf16x8 a[8];
  const float* crow = C + (size_t)row * EMB;
#pragma unroll
  for (int s = 0; s < 8; ++s) {
    const f32x4* p = (const f32x4*)(crow + s * 32 + l4 * 8);
    a[s] = cvt8(p[0], p[1]);
  }
  const int row_o_base = blockIdx.x * 64 + wv * 16 + l4 * 4;
  for (int ct = 0; ct < 8; ++ct) {
    f32x4 acc[4];
#pragma unroll
    for (int nf = 0; nf < 4; ++nf) acc[nf] = (f32x4){0.f, 0.f, 0.f, 0.f};
#pragma unroll
    for (int s = 0; s < 8; ++s) {
#pragma unroll
      for (int nf = 0; nf < 4; ++nf) {
        int col = ct * 64 + nf * 16 + l15;
        const f32x4* bp = (const f32x4*)(Wax + (size_t)col * EMB + s * 32 + l4 * 8);
        bf16x8 b = cvt8(bp[0], bp[1]);
        acc[nf] = mfma16(a[s], b, acc[nf]);
      }
    }
#pragma unroll
    for (int nf = 0; nf < 4; ++nf) {
      int col = ct * 64 + nf * 16 + l15;
#pragma unroll
      for (int r = 0; r < 4; ++r)
        CW[(size_t)(row_o_base + r) * HID + col] = (unsigned short)f2bf(acc[nf][r]);
    }
  }
}

// ---- the recurrent scan (NS = ring depth, runtime: 8 preferred, 4 fallback) ----
__global__ void __launch_bounds__(256, 1) k_scan(
    const int* __restrict__ X, const float* __restrict__ Waa, const float* __restrict__ Wal,
    const float* __restrict__ ba, const unsigned short* __restrict__ CW,
    unsigned short* __restrict__ h0buf, unsigned short* __restrict__ h1buf,
    unsigned* __restrict__ flags, int NS) {
  extern __shared__ unsigned short lds[];
  unsigned short* ldsWaa = lds;                 // [64][512] bf16, 16B-unit swizzled
  unsigned short* ldsWal = lds + 64 * 512;
  unsigned short* packb  = lds + 2 * 64 * 512;  // 4 waves x 512 shorts (private)
  const int tid = threadIdx.x, lane = tid & 63, wv = tid >> 6;
  const int l15 = lane & 15, l4 = lane >> 4;
  const int g = blockIdx.x & 7, mem = blockIdx.x >> 3;
  const int colslice = mem * 64;
  const int NM = NS - 1;                        // ring mask (NS power of 2)
  unsigned* fl = flags + g * (32 * FSTRIDE);    // 32 flags x 128B lines per group
  unsigned* f0 = fl;                            // flags 0..15: h0 (2 per member)
  unsigned* f1 = fl + 16 * FSTRIDE;             // flags 16..31: h1

  // stage weight slices f32 -> bf16 LDS, 16B-unit swizzled
  for (int c = tid; c < 64 * 64; c += 256) {
    int row = c >> 6, u = c & 63, us = u ^ (row & 7);
    {
      const f32x4* p = (const f32x4*)(Waa + (size_t)(colslice + row) * HID + u * 8);
      *(bf16x8*)(ldsWaa + row * 512 + us * 8) = cvt8(p[0], p[1]);
    }
    {
      const f32x4* p = (const f32x4*)(Wal + (size_t)(colslice + row) * HID + u * 8);
      *(bf16x8*)(ldsWal + row * 512 + us * 8) = cvt8(p[0], p[1]);
    }
  }

  // per-wave geometry: each wave owns 2 col-tiles (32 cols)
  const int cb  = (wv & 1) * 2;                  // col-tile base within slice
  const int jc0 = colslice + cb * 16 + l15;      // out col, chain 0
  const int jc1 = jc0 + 16;                      // out col, chain 1
  const float ba0 = ba[jc0], ba1 = ba[jc1];
  const int wb0 = (cb * 16 + l15) * 512;         // LDS weight row base
  const int wb1 = wb0 + 16 * 512;
  const int swz = l15 & 7;
  const int aoff = l4 * 128 + l15 * 8;           // A-frag lane offset (shorts)
  // per-wave LDS pack region + offsets
  unsigned short* pk = packb + wv * 512;
  const int pl0 = ((l15 >> 3) + 0) * 128 + (l4 * 4) * 8 + (l15 & 7);
  const int pl1 = ((l15 >> 3) + 2) * 128 + (l4 * 4) * 8 + (l15 & 7);
  const int stbase = mem * 1024 + cb * 256 + lane * 8;  // wave's contiguous 1KB region
  const int brow = g * 16 + l4 * 4;
  unsigned short* h0g = h0buf + (size_t)g * ((size_t)NS * SLOT);
  unsigned short* h1g = h1buf + (size_t)g * ((size_t)NS * SLOT);
  __syncthreads();

#define WFRAG(W, wb, s) (*(const bf16x8*)((W) + (wb) + ((((s) * 4 + l4) ^ swz) * 8)))
#define LOAD16(arr, base)                                                         \
  _Pragma("unroll") for (int s = 0; s < 16; ++s)                                  \
    asm volatile("global_load_dwordx4 %0, %1, off sc0 sc1"                        \
                 : "=v"(arr[s]) : "v"((base) + s * 1024) : "memory");

  if (wv < 2) {
    // ================= h0 producers (waves 0,1) =================
    unsigned* myf = f0 + (2 * mem + (wv & 1)) * FSTRIDE;
    int idxA[4];
    unsigned cw0[4], cw1[4];
    unsigned pv0 = 0, pv1 = 0;
    { // prologue: idx(0) -> cw(0) gathers; then idx(1)
      int id0[4];
#pragma unroll
      for (int r = 0; r < 4; ++r)
        asm volatile("global_load_dword %0, %1, off"
                     : "=v"(id0[r]) : "v"(X + (size_t)(brow + r) * SEQ) : "memory");
      VMCNT0; SCHED0;
#pragma unroll
      for (int r = 0; r < 4; ++r) {
        const unsigned short* c0 = CW + (size_t)id0[r] * HID + jc0;
        asm volatile("global_load_ushort %0, %1, off" : "=v"(cw0[r]) : "v"(c0) : "memory");
        asm volatile("global_load_ushort %0, %1, off" : "=v"(cw1[r]) : "v"(c0 + 16) : "memory");
      }
#pragma unroll
      for (int r = 0; r < 4; ++r)
        asm volatile("global_load_dword %0, %1, off"
                     : "=v"(idxA[r]) : "v"(X + (size_t)(brow + r) * SEQ + 1) : "memory");
    }
    const int bpk = NS - 2;   // h1 may lag this many steps before h0 stalls
    for (int t = 0; t < SEQ; ++t) {
      pollD2(f0, f1, (unsigned)t, (unsigned)(t >= bpk ? t - bpk : 0), pv0, pv1);
      bf16x8 a0[16];
      const char* pa0 = (const char*)(h0g + (size_t)((t + NM) & NM) * SLOT + aoff);
      LOAD16(a0, pa0)
      VMCNT0; SCHED0;                      // volley + poll strays retired
      PIN2(pv0, pv1);
      f32x4 acc0 = (f32x4){0.f, 0.f, 0.f, 0.f};
      f32x4 acc1 = (f32x4){0.f, 0.f, 0.f, 0.f};
#pragma unroll
      for (int s = 0; s < 16; ++s) {
        bf16x8 a = a0[s];
        acc0 = mfma16(a, WFRAG(ldsWaa, wb0, s), acc0);
        acc1 = mfma16(a, WFRAG(ldsWaa, wb1, s), acc1);
      }
#pragma unroll
      for (int r = 0; r < 4; ++r) {
        float v0 = fast_tanh(acc0[r] + bf2f((unsigned short)cw0[r]) + ba0);
        float v1 = fast_tanh(acc1[r] + bf2f((unsigned short)cw1[r]) + ba1);
        pk[pl0 + r * 8] = (unsigned short)f2bf(v0);
        pk[pl1 + r * 8] = (unsigned short)f2bf(v1);
      }
      LGKM0; SCHED0;                       // wave-private pack complete
      bf16x8 ov = *(const bf16x8*)(pk + lane * 8);
      st16(h0g + (size_t)(t & NM) * SLOT + stbase, ov);
      VMCNT0;                              // store at coherent point
      if (lane == 0) sig(myf, (unsigned)(t + 1));
      // tail prefetches: cw(t+1) via idxA (=X(t+1), drained), then idxA <- X(t+2)
#pragma unroll
      for (int r = 0; r < 4; ++r) {
        const unsigned short* c0 = CW + (size_t)idxA[r] * HID + jc0;
        asm volatile("global_load_ushort %0, %1, off" : "=v"(cw0[r]) : "v"(c0) : "memory");
        asm volatile("global_load_ushort %0, %1, off" : "=v"(cw1[r]) : "v"(c0 + 16) : "memory");
      }
      const int tp = (t + 2 < SEQ) ? t + 2 : SEQ - 1;
#pragma unroll
      for (int r = 0; r < 4; ++r)
        asm volatile("global_load_dword %0, %1, off"
                     : "=v"(idxA[r]) : "v"(X + (size_t)(brow + r) * SEQ + tp) : "memory");
    }
    VMCNT0; PIN2(pv0, pv1);                // retire any final stray
  } else {
    // ================= h1 producers (waves 2,3): step t computes h1(t-1) =========
    unsigned* myf = f1 + (2 * mem + (wv & 1)) * FSTRIDE;
    unsigned pv0 = 0, pv1 = 0;
    for (int t = 0; t <= SEQ; ++t) {
      pollD2(f0, f1, (unsigned)t, (unsigned)t, pv0, pv1);
      if (t >= 1) {
        bf16x8 a1[16], a2[16];
        const char* pa1 = (const char*)(h0g + (size_t)((t + NM) & NM) * SLOT + aoff);      // h0(t-1)
        const char* pa2 = (const char*)(h1g + (size_t)((t + NM - 1) & NM) * SLOT + aoff);  // h1(t-2)
        LOAD16(a1, pa1)
        LOAD16(a2, pa2)
        VMCNT16; SCHED0;                   // a1 ready; poll strays retired (oldest)
        PIN2(pv0, pv1);
        f32x4 acc0 = (f32x4){0.f, 0.f, 0.f, 0.f};
        f32x4 acc1 = (f32x4){0.f, 0.f, 0.f, 0.f};
#pragma unroll
        for (int s = 0; s < 16; ++s) {
          bf16x8 a = a1[s];
          acc0 = mfma16(a, WFRAG(ldsWal, wb0, s), acc0);
          acc1 = mfma16(a, WFRAG(ldsWal, wb1, s), acc1);
        }
        VMCNT0; SCHED0;                    // a2 ready
#pragma unroll
        for (int s = 0; s < 16; ++s) {
          bf16x8 a = a2[s];
          acc0 = mfma16(a, WFRAG(ldsWaa, wb0, s), acc0);
          acc1 = mfma16(a, WFRAG(ldsWaa, wb1, s), acc1);
        }
#pragma unroll
        for (int r = 0; r < 4; ++r) {
          float v0 = fast_tanh(acc0[r] + ba0);
          float v1 = fast_tanh(acc1[r] + ba1);
          pk[pl0 + r * 8] = (unsigned short)f2bf(v0);
          pk[pl1 + r * 8] = (unsigned short)f2bf(v1);
        }
        LGKM0; SCHED0;
        bf16x8 ov = *(const bf16x8*)(pk + lane * 8);
        st16(h1g + (size_t)((t + NM) & NM) * SLOT + stbase, ov);   // h1(t-1)
        VMCNT0;
      } else {
        VMCNT0; SCHED0; PIN2(pv0, pv1);    // t=0: retire poll strays explicitly
      }
      if (lane == 0) sig(myf, (unsigned)(t + 1));
    }
    VMCNT0; PIN2(pv0, pv1);                // retire any final stray
  }
#undef LOAD16
#undef WFRAG
}

// ---- out = h1_final @ W_out.T + b_out  (M=128, N=32000, K=512) ----
__global__ void __launch_bounds__(256) k_out(const float* __restrict__ Wout,
                                             const float* __restrict__ bout,
                                             const unsigned short* __restrict__ h1buf,
                                             float* __restrict__ out, int NS) {
  const int tid = threadIdx.x, lane = tid & 63, wv = tid >> 6;
  const int l15 = lane & 15, l4 = lane >> 4;
  const int col = blockIdx.x * 64 + wv * 16 + l15;
  const float bo = bout[col];
  const int finslot = (SEQ - 1) & (NS - 1);
  f32x4 acc[8];
#pragma unroll
  for (int rt = 0; rt < 8; ++rt) acc[rt] = (f32x4){0.f, 0.f, 0.f, 0.f};
  const int aoff = l4 * 128 + l15 * 8;
#pragma unroll 4
  for (int s = 0; s < 16; ++s) {
    const f32x4* bp = (const f32x4*)(Wout + (size_t)col * HID + s * 32 + l4 * 8);
    bf16x8 b = cvt8(bp[0], bp[1]);
#pragma unroll
    for (int rt = 0; rt < 8; ++rt) {
      const unsigned short* ap = h1buf + ((size_t)rt * NS + finslot) * SLOT + aoff + s * 512;
      acc[rt] = mfma16(*(const bf16x8*)ap, b, acc[rt]);
    }
  }
#pragma unroll
  for (int rt = 0; rt < 8; ++rt) {
#pragma unroll
    for (int r = 0; r < 4; ++r) {
      int row = rt * 16 + l4 * 4 + r;
      out[(size_t)row * VOCAB + col] = acc[rt][r] + bo;
    }
  }
}

extern "C" void kernel_launch(void* const* d_in, const int* in_sizes, int n_in,
                              void* d_out, int out_size, void* d_ws, size_t ws_size,
                              hipStream_t stream) {
  const int*   X    = (const int*)d_in[0];
  const float* C    = (const float*)d_in[1];
  const float* Wax  = (const float*)d_in[2];
  const float* Waa  = (const float*)d_in[3];
  const float* Wal  = (const float*)d_in[4];
  const float* ba   = (const float*)d_in[5];
  const float* Wout = (const float*)d_in[6];
  const float* bout = (const float*)d_in[7];
  float* out = (float*)d_out;
  char* ws = (char*)d_ws;
  (void)in_sizes; (void)n_in; (void)out_size;

  const size_t cw_bytes = (size_t)VOCAB * HID * 2;          // 32,768,000
  const size_t fl_bytes = 8ull * 32 * FSTRIDE * 4;          // 32 KB
  const size_t hb8 = 8ull * 8 * SLOT * 2;                   // 1,048,576 per tensor
  const size_t hb4 = 8ull * 4 * SLOT * 2;                   //   524,288 per tensor
  int NS; size_t h_bytes;
  if      (ws_size >= cw_bytes + 2 * hb8 + fl_bytes) { NS = 8; h_bytes = hb8; }
  else if (ws_size >= cw_bytes + 2 * hb4 + fl_bytes) { NS = 4; h_bytes = hb4; }
  else return;                                              // visible failure

  unsigned short* CWp = (unsigned short*)(ws);
  unsigned short* h0  = (unsigned short*)(ws + cw_bytes);
  unsigned short* h1  = (unsigned short*)(ws + cw_bytes + h_bytes);
  unsigned*       fl  = (unsigned*)(ws + cw_bytes + 2 * h_bytes);

  const int zero_words = (int)((2 * h_bytes + fl_bytes) / 4);
  hipLaunchKernelGGL(k_init, dim3((zero_words + 255) / 256), dim3(256), 0, stream,
                     (unsigned*)(ws + cw_bytes), zero_words);
  hipLaunchKernelGGL(k_cw, dim3(VOCAB / 64), dim3(256), 0, stream, C, Wax, CWp);
  hipFuncSetAttribute((const void*)k_scan, hipFuncAttributeMaxDynamicSharedMemorySize, 135168);
  hipLaunchKernelGGL(k_scan, dim3(64), dim3(256), 135168, stream,
                     X, Waa, Wal, ba, CWp, h0, h1, fl, NS);
  hipLaunchKernelGGL(k_out, dim3(VOCAB / 64), dim3(256), 0, stream, Wout, bout, h1, out, NS);
}

// Round 17
// 1869.049 us; speedup vs baseline: 1.1127x; 1.1127x over previous
//
#include <hip/hip_runtime.h>
#include <hip/hip_bf16.h>
#include <stdint.h>

// TextRNN: 2-layer tanh RNN. B=128,T=512,H=512,E=256,V=32000.
// R17 "sentinel slots": data IS the flag. All exchanged values are tanh outputs
//   (bf16 in [-1,1], never 0xFFFF). Slots pre-filled 0xFFFF; producers store
//   fire-and-forget; consumers retry volleys until no unit shows 0xFFFF in
//   short[1] (one dwordx4 store = one 16B transaction). Deletes drain+sig+detect
//   legs -> ~2 RTT/step. ABA closed: re-sentinel slot (t+2) at step t; any
//   consumer reaching the reader step has causally observed a producer store
//   that FOLLOWED that producer's sentinel-draining vmcnt (proof in journal).
//   h1-lag gate (f1 >= t-5) merged into h0's volley (1 extra flag load, 0 legs).
// R16 post-mortem: depth-2 poll +12% -> flag-protocol legs can't be tuned away;
//   leg DELETION is the only path below ~3.4us/step.

#define VOCAB 32000
#define EMB   256
#define HID   512
#define SEQ   512
#define SLOT  8192          // one time-slot: 64 units * 16 rows * 8 shorts
#define NS    8
#define NM    7
#define FSTRIDE 32          // one flag per 128B line

typedef __attribute__((ext_vector_type(8))) short bf16x8;
typedef __attribute__((ext_vector_type(4))) float f32x4;

__device__ inline short f2bf(float f) {
  union { float f; uint32_t u; } v; v.f = f;
  uint32_t u = v.u;
  uint32_t r = (u + 0x7FFFu + ((u >> 16) & 1u)) >> 16;
  return (short)r;
}
__device__ inline float bf2f(unsigned short s) {
  union { uint32_t u; float f; } v; v.u = ((uint32_t)s) << 16;
  return v.f;
}
__device__ inline bf16x8 cvt8(f32x4 x0, f32x4 x1) {
  bf16x8 r;
  r[0]=f2bf(x0[0]); r[1]=f2bf(x0[1]); r[2]=f2bf(x0[2]); r[3]=f2bf(x0[3]);
  r[4]=f2bf(x1[0]); r[5]=f2bf(x1[1]); r[6]=f2bf(x1[2]); r[7]=f2bf(x1[3]);
  return r;
}
__device__ inline f32x4 mfma16(bf16x8 a, bf16x8 b, f32x4 c) {
  return __builtin_amdgcn_mfma_f32_16x16x32_bf16(a, b, c, 0, 0, 0);
}
__device__ inline float fast_tanh(float x) {
  x = fminf(30.f, fmaxf(-30.f, x));
  float e = __expf(2.f * x);
  return (e - 1.f) * __builtin_amdgcn_rcpf(e + 1.f);
}

#define VMCNT0  asm volatile("s_waitcnt vmcnt(0)" ::: "memory")
#define LGKM0   asm volatile("s_waitcnt lgkmcnt(0)" ::: "memory")
#define SCHED0  __builtin_amdgcn_sched_barrier(0)

__device__ inline void st16(unsigned short* p, bf16x8 v) {
  asm volatile("global_store_dwordx4 %0, %1, off sc0 sc1" :: "v"(p), "v"(v) : "memory");
}
__device__ inline void sig(unsigned* p, unsigned v) {
  asm volatile("global_store_dword %0, %1, off sc0 sc1" :: "v"(p), "v"(v) : "memory");
}
#define LOAD16(arr, base)                                                         \
  _Pragma("unroll") for (int s = 0; s < 16; ++s)                                  \
    asm volatile("global_load_dwordx4 %0, %1, off sc0 sc1"                        \
                 : "=v"(arr[s]) : "v"((base) + s * 1024) : "memory");
// sentinel test: short[1] of each 16B unit is a tanh bf16 -> never 0xFFFF
__device__ inline unsigned sbad(const bf16x8* a) {
  unsigned bad = 0;
#pragma unroll
  for (int s = 0; s < 16; ++s) bad |= ((unsigned short)a[s][1] == 0xFFFFu);
  return bad;
}

__global__ void k_fill(unsigned* __restrict__ p, int n, unsigned val) {
  int i = blockIdx.x * 256 + threadIdx.x;
  if (i < n) p[i] = val;
}
// zero slot NM of both rings (h(-1)=0 state) + flags
__global__ void k_zslots(unsigned* __restrict__ h0, unsigned* __restrict__ h1,
                         unsigned* __restrict__ fl) {
  int i = blockIdx.x * 256 + threadIdx.x;
  const int perT = 8 * (SLOT / 2);            // 8 groups x 4096 words
  if (i < perT) {
    int g = i / (SLOT / 2), o = i % (SLOT / 2);
    h0[(size_t)(g * NS + NM) * (SLOT / 2) + o] = 0u;
  } else if (i < 2 * perT) {
    int j = i - perT;
    int g = j / (SLOT / 2), o = j % (SLOT / 2);
    h1[(size_t)(g * NS + NM) * (SLOT / 2) + o] = 0u;
  } else if (i < 2 * perT + 8 * 32 * FSTRIDE) {
    fl[i - 2 * perT] = 0u;
  }
}

// ---- CW = C @ W_ax.T  (M=32000, N=512, K=256), bf16 out ----
__global__ void __launch_bounds__(256) k_cw(const float* __restrict__ C,
                                            const float* __restrict__ Wax,
                                            unsigned short* __restrict__ CW) {
  const int tid = threadIdx.x, lane = tid & 63, wv = tid >> 6;
  const int l15 = lane & 15, l4 = lane >> 4;
  const int row = blockIdx.x * 64 + wv * 16 + l15;
  bf16x8 a[8];
  const float* crow = C + (size_t)row * EMB;
#pragma unroll
  for (int s = 0; s < 8; ++s) {
    const f32x4* p = (const f32x4*)(crow + s * 32 + l4 * 8);
    a[s] = cvt8(p[0], p[1]);
  }
  const int row_o_base = blockIdx.x * 64 + wv * 16 + l4 * 4;
  for (int ct = 0; ct < 8; ++ct) {
    f32x4 acc[4];
#pragma unroll
    for (int nf = 0; nf < 4; ++nf) acc[nf] = (f32x4){0.f, 0.f, 0.f, 0.f};
#pragma unroll
    for (int s = 0; s < 8; ++s) {
#pragma unroll
      for (int nf = 0; nf < 4; ++nf) {
        int col = ct * 64 + nf * 16 + l15;
        const f32x4* bp = (const f32x4*)(Wax + (size_t)col * EMB + s * 32 + l4 * 8);
        bf16x8 b = cvt8(bp[0], bp[1]);
        acc[nf] = mfma16(a[s], b, acc[nf]);
      }
    }
#pragma unroll
    for (int nf = 0; nf < 4; ++nf) {
      int col = ct * 64 + nf * 16 + l15;
#pragma unroll
      for (int r = 0; r < 4; ++r)
        CW[(size_t)(row_o_base + r) * HID + col] = (unsigned short)f2bf(acc[nf][r]);
    }
  }
}

// ---- the recurrent scan ----
__global__ void __launch_bounds__(256, 1) k_scan(
    const int* __restrict__ X, const float* __restrict__ Waa, const float* __restrict__ Wal,
    const float* __restrict__ ba, const unsigned short* __restrict__ CW,
    unsigned short* __restrict__ h0buf, unsigned short* __restrict__ h1buf,
    unsigned* __restrict__ flags) {
  extern __shared__ unsigned short lds[];
  unsigned short* ldsWaa = lds;                 // [64][512] bf16, 16B-unit swizzled
  unsigned short* ldsWal = lds + 64 * 512;
  unsigned short* packb  = lds + 2 * 64 * 512;  // 4 waves x 512 shorts (private)
  const int tid = threadIdx.x, lane = tid & 63, wv = tid >> 6;
  const int l15 = lane & 15, l4 = lane >> 4;
  const int g = blockIdx.x & 7, mem = blockIdx.x >> 3;
  const int colslice = mem * 64;
  unsigned* f1 = flags + g * (32 * FSTRIDE) + 16 * FSTRIDE;  // 16 h1-progress flags

  // stage weight slices f32 -> bf16 LDS, 16B-unit swizzled
  for (int c = tid; c < 64 * 64; c += 256) {
    int row = c >> 6, u = c & 63, us = u ^ (row & 7);
    {
      const f32x4* p = (const f32x4*)(Waa + (size_t)(colslice + row) * HID + u * 8);
      *(bf16x8*)(ldsWaa + row * 512 + us * 8) = cvt8(p[0], p[1]);
    }
    {
      const f32x4* p = (const f32x4*)(Wal + (size_t)(colslice + row) * HID + u * 8);
      *(bf16x8*)(ldsWal + row * 512 + us * 8) = cvt8(p[0], p[1]);
    }
  }

  // per-wave geometry: each wave owns 2 col-tiles (32 cols)
  const int cb  = (wv & 1) * 2;
  const int jc0 = colslice + cb * 16 + l15;
  const int jc1 = jc0 + 16;
  const float ba0 = ba[jc0], ba1 = ba[jc1];
  const int wb0 = (cb * 16 + l15) * 512;
  const int wb1 = wb0 + 16 * 512;
  const int swz = l15 & 7;
  const int aoff = l4 * 128 + l15 * 8;           // A-frag lane offset (shorts)
  unsigned short* pk = packb + wv * 512;
  const int pl0 = ((l15 >> 3) + 0) * 128 + (l4 * 4) * 8 + (l15 & 7);
  const int pl1 = ((l15 >> 3) + 2) * 128 + (l4 * 4) * 8 + (l15 & 7);
  const int stbase = mem * 1024 + cb * 256 + lane * 8;  // wave's contiguous 1KB region
  const int brow = g * 16 + l4 * 4;
  unsigned short* h0g = h0buf + (size_t)g * ((size_t)NS * SLOT);
  unsigned short* h1g = h1buf + (size_t)g * ((size_t)NS * SLOT);
  bf16x8 SENT;
#pragma unroll
  for (int i = 0; i < 8; ++i) SENT[i] = (short)0xFFFF;
  __syncthreads();

#define WFRAG(W, wb, s) (*(const bf16x8*)((W) + (wb) + ((((s) * 4 + l4) ^ swz) * 8)))

  if (wv < 2) {
    // ================= h0 producers (waves 0,1) =================
    int idxA[4];
    unsigned cw0[4], cw1[4];
    { // prologue: idx(0) -> cw(0) gathers; then idx(1)
      int id0[4];
#pragma unroll
      for (int r = 0; r < 4; ++r)
        asm volatile("global_load_dword %0, %1, off"
                     : "=v"(id0[r]) : "v"(X + (size_t)(brow + r) * SEQ) : "memory");
      VMCNT0; SCHED0;
#pragma unroll
      for (int r = 0; r < 4; ++r) {
        const unsigned short* c0 = CW + (size_t)id0[r] * HID + jc0;
        asm volatile("global_load_ushort %0, %1, off" : "=v"(cw0[r]) : "v"(c0) : "memory");
        asm volatile("global_load_ushort %0, %1, off" : "=v"(cw1[r]) : "v"(c0 + 16) : "memory");
      }
#pragma unroll
      for (int r = 0; r < 4; ++r)
        asm volatile("global_load_dword %0, %1, off"
                     : "=v"(idxA[r]) : "v"(X + (size_t)(brow + r) * SEQ + 1) : "memory");
    }
    const unsigned* myfl = f1 + l15 * FSTRIDE;   // lane<16's h1-progress flag
    for (int t = 0; t < SEQ; ++t) {
      // combined retry: a0 = h0(t-1) sentinel-clean AND (lane<16) f1 >= t-5
      bf16x8 a0[16];
      const char* pa0 = (const char*)(h0g + (size_t)((t + NM) & NM) * SLOT + aoff);
      const unsigned ftgt = (t >= 5) ? (unsigned)(t - 5) : 0u;
      {
        int gd = 0;
        while (true) {
          unsigned fv = 0;
          LOAD16(a0, pa0)
          if (lane < 16)
            asm volatile("global_load_dword %0, %1, off sc0 sc1"
                         : "=v"(fv) : "v"(myfl) : "memory");
          VMCNT0; SCHED0;
          bool ok = (sbad(a0) == 0u) && ((lane >= 16) || (fv >= ftgt));
          if (__ballot(ok) == ~0ull) break;
          __builtin_amdgcn_s_sleep(1);
          if (++gd > 30000) break;   // fail visibly, never hang the harness
        }
      }
      f32x4 acc0 = (f32x4){0.f, 0.f, 0.f, 0.f};
      f32x4 acc1 = (f32x4){0.f, 0.f, 0.f, 0.f};
#pragma unroll
      for (int s = 0; s < 16; ++s) {
        bf16x8 a = a0[s];
        acc0 = mfma16(a, WFRAG(ldsWaa, wb0, s), acc0);
        acc1 = mfma16(a, WFRAG(ldsWaa, wb1, s), acc1);
      }
#pragma unroll
      for (int r = 0; r < 4; ++r) {
        float v0 = fast_tanh(acc0[r] + bf2f((unsigned short)cw0[r]) + ba0);
        float v1 = fast_tanh(acc1[r] + bf2f((unsigned short)cw1[r]) + ba1);
        pk[pl0 + r * 8] = (unsigned short)f2bf(v0);
        pk[pl1 + r * 8] = (unsigned short)f2bf(v1);
      }
      LGKM0; SCHED0;
      bf16x8 ov = *(const bf16x8*)(pk + lane * 8);
      st16(h0g + (size_t)(t & NM) * SLOT + stbase, ov);          // fire-and-forget
      if (t < SEQ - 2)                                           // re-sentinel d=2
        st16(h0g + (size_t)((t + 2) & NM) * SLOT + stbase, SENT);
      // tail prefetches: cw(t+1) via idxA (=X(t+1), drained), then idxA <- X(t+2)
#pragma unroll
      for (int r = 0; r < 4; ++r) {
        const unsigned short* c0 = CW + (size_t)idxA[r] * HID + jc0;
        asm volatile("global_load_ushort %0, %1, off" : "=v"(cw0[r]) : "v"(c0) : "memory");
        asm volatile("global_load_ushort %0, %1, off" : "=v"(cw1[r]) : "v"(c0 + 16) : "memory");
      }
      const int tp = (t + 2 < SEQ) ? t + 2 : SEQ - 1;
#pragma unroll
      for (int r = 0; r < 4; ++r)
        asm volatile("global_load_dword %0, %1, off"
                     : "=v"(idxA[r]) : "v"(X + (size_t)(brow + r) * SEQ + tp) : "memory");
    }
    VMCNT0;
  } else {
    // ========== h1 producers (waves 2,3): step t computes h1(t-1), t=1..SEQ ======
    unsigned* myf = f1 + (2 * mem + (wv & 1)) * FSTRIDE;
    for (int t = 1; t <= SEQ; ++t) {
      bf16x8 a1[16], a2[16];
      const char* pa1 = (const char*)(h0g + (size_t)((t + NM) & NM) * SLOT + aoff);      // h0(t-1)
      const char* pa2 = (const char*)(h1g + (size_t)((t + NM - 1) & NM) * SLOT + aoff);  // h1(t-2)
      {
        int gd = 0;
        while (true) {
          LOAD16(a1, pa1)
          LOAD16(a2, pa2)
          VMCNT0; SCHED0;
          bool ok = ((sbad(a1) | sbad(a2)) == 0u);
          if (__ballot(ok) == ~0ull) break;
          __builtin_amdgcn_s_sleep(1);
          if (++gd > 30000) break;   // fail visibly
        }
      }
      if (lane == 0) sig(myf, (unsigned)t);   // progress post (loads retired above)
      f32x4 acc0 = (f32x4){0.f, 0.f, 0.f, 0.f};
      f32x4 acc1 = (f32x4){0.f, 0.f, 0.f, 0.f};
#pragma unroll
      for (int s = 0; s < 16; ++s) {
        bf16x8 a = a1[s];
        acc0 = mfma16(a, WFRAG(ldsWal, wb0, s), acc0);
        acc1 = mfma16(a, WFRAG(ldsWal, wb1, s), acc1);
      }
#pragma unroll
      for (int s = 0; s < 16; ++s) {
        bf16x8 a = a2[s];
        acc0 = mfma16(a, WFRAG(ldsWaa, wb0, s), acc0);
        acc1 = mfma16(a, WFRAG(ldsWaa, wb1, s), acc1);
      }
#pragma unroll
      for (int r = 0; r < 4; ++r) {
        float v0 = fast_tanh(acc0[r] + ba0);
        float v1 = fast_tanh(acc1[r] + ba1);
        pk[pl0 + r * 8] = (unsigned short)f2bf(v0);
        pk[pl1 + r * 8] = (unsigned short)f2bf(v1);
      }
      LGKM0; SCHED0;
      bf16x8 ov = *(const bf16x8*)(pk + lane * 8);
      st16(h1g + (size_t)((t + NM) & NM) * SLOT + stbase, ov);   // h1(t-1), fire-forget
      if (t <= SEQ - 2)                                          // re-sentinel d=2
        st16(h1g + (size_t)((t + 1) & NM) * SLOT + stbase, SENT);
    }
    VMCNT0;
  }
#undef WFRAG
}

// ---- out = h1_final @ W_out.T + b_out  (M=128, N=32000, K=512) ----
__global__ void __launch_bounds__(256) k_out(const float* __restrict__ Wout,
                                             const float* __restrict__ bout,
                                             const unsigned short* __restrict__ h1buf,
                                             float* __restrict__ out) {
  const int tid = threadIdx.x, lane = tid & 63, wv = tid >> 6;
  const int l15 = lane & 15, l4 = lane >> 4;
  const int col = blockIdx.x * 64 + wv * 16 + l15;
  const float bo = bout[col];
  const int finslot = (SEQ - 1) & NM;           // slot 7 holds h1(511)
  f32x4 acc[8];
#pragma unroll
  for (int rt = 0; rt < 8; ++rt) acc[rt] = (f32x4){0.f, 0.f, 0.f, 0.f};
  const int aoff = l4 * 128 + l15 * 8;
#pragma unroll 4
  for (int s = 0; s < 16; ++s) {
    const f32x4* bp = (const f32x4*)(Wout + (size_t)col * HID + s * 32 + l4 * 8);
    bf16x8 b = cvt8(bp[0], bp[1]);
#pragma unroll
    for (int rt = 0; rt < 8; ++rt) {
      const unsigned short* ap = h1buf + ((size_t)rt * NS + finslot) * SLOT + aoff + s * 512;
      acc[rt] = mfma16(*(const bf16x8*)ap, b, acc[rt]);
    }
  }
#pragma unroll
  for (int rt = 0; rt < 8; ++rt) {
#pragma unroll
    for (int r = 0; r < 4; ++r) {
      int row = rt * 16 + l4 * 4 + r;
      out[(size_t)row * VOCAB + col] = acc[rt][r] + bo;
    }
  }
}

extern "C" void kernel_launch(void* const* d_in, const int* in_sizes, int n_in,
                              void* d_out, int out_size, void* d_ws, size_t ws_size,
                              hipStream_t stream) {
  const int*   X    = (const int*)d_in[0];
  const float* C    = (const float*)d_in[1];
  const float* Wax  = (const float*)d_in[2];
  const float* Waa  = (const float*)d_in[3];
  const float* Wal  = (const float*)d_in[4];
  const float* ba   = (const float*)d_in[5];
  const float* Wout = (const float*)d_in[6];
  const float* bout = (const float*)d_in[7];
  float* out = (float*)d_out;
  char* ws = (char*)d_ws;
  (void)in_sizes; (void)n_in; (void)out_size;

  const size_t cw_bytes = (size_t)VOCAB * HID * 2;          // 32,768,000
  const size_t hb = 8ull * NS * SLOT * 2;                   // 1,048,576 per tensor
  const size_t fl_bytes = 8ull * 32 * FSTRIDE * 4;          // 32 KB
  if (ws_size < cw_bytes + 2 * hb + fl_bytes) return;       // visible failure

  unsigned short* CWp = (unsigned short*)(ws);
  unsigned short* h0  = (unsigned short*)(ws + cw_bytes);
  unsigned short* h1  = (unsigned short*)(ws + cw_bytes + hb);
  unsigned*       fl  = (unsigned*)(ws + cw_bytes + 2 * hb);

  const int ring_words = (int)(hb / 4);                     // 262,144 words per tensor
  hipLaunchKernelGGL(k_fill, dim3((ring_words + 255) / 256), dim3(256), 0, stream,
                     (unsigned*)h0, ring_words, 0xFFFFFFFFu);
  hipLaunchKernelGGL(k_fill, dim3((ring_words + 255) / 256), dim3(256), 0, stream,
                     (unsigned*)h1, ring_words, 0xFFFFFFFFu);
  const int zn = 2 * 8 * (SLOT / 2) + 8 * 32 * FSTRIDE;     // slot-7 zeros + flags
  hipLaunchKernelGGL(k_zslots, dim3((zn + 255) / 256), dim3(256), 0, stream,
                     (unsigned*)h0, (unsigned*)h1, fl);
  hipLaunchKernelGGL(k_cw, dim3(VOCAB / 64), dim3(256), 0, stream, C, Wax, CWp);
  hipFuncSetAttribute((const void*)k_scan, hipFuncAttributeMaxDynamicSharedMemorySize, 135168);
  hipLaunchKernelGGL(k_scan, dim3(64), dim3(256), 135168, stream,
                     X, Waa, Wal, ba, CWp, h0, h1, fl);
  hipLaunchKernelGGL(k_out, dim3(VOCAB / 64), dim3(256), 0, stream, Wout, bout, h1, out);
}